// Round 1
// baseline (20450.508 us; speedup 1.0000x reference)
//
#include <hip/hip_runtime.h>
#include <float.h>
#include <math.h>

#define B_ 8
#define C_ 256
#define H_ 96
#define W_ 96
#define HW_ 9216
#define NQ_ 100
#define EPS_ 1e-6f

// ---------------------------------------------------------------------------
// Fused head: conv3x3(+bias,relu) -> conv1x1, partial over 32-channel chunks.
// 1 wave/block, 8x8 pixel tile, weights via wave-uniform (scalar) loads.
// grid (12,12, B*8): z = b*8 + chunk. Writes partial logits (chunk 0 adds b2).
// ---------------------------------------------------------------------------
template<int K>
__global__ __launch_bounds__(64)
void head_part_kernel(const float* __restrict__ x,
                      const float* __restrict__ w1, const float* __restrict__ b1,
                      const float* __restrict__ w2, const float* __restrict__ b2,
                      float* __restrict__ part)
{
    const int tid = threadIdx.x;
    const int tx = tid & 7, ty = tid >> 3;
    const int x0 = blockIdx.x * 8, y0 = blockIdx.y * 8;
    const int b  = blockIdx.z >> 3;
    const int ch = blockIdx.z & 7;
    const int oc0 = ch * 32;
    const int gx = x0 + tx, gy = y0 + ty;

    __shared__ float xs[4][10][12];

    float lacc[K];
#pragma unroll
    for (int k = 0; k < K; ++k) lacc[k] = (ch == 0) ? b2[k] : 0.f;

    float acc[32];
#pragma unroll
    for (int o = 0; o < 32; ++o) acc[o] = 0.f;

    const float* xb = x + (size_t)b * C_ * HW_;

#pragma unroll 1
    for (int ci0 = 0; ci0 < C_; ci0 += 4) {
        __syncthreads();
        for (int t = tid; t < 400; t += 64) {
            int s = t / 100, r = t % 100;
            int row = r / 10, col = r % 10;
            int yy = y0 - 1 + row, xx = x0 - 1 + col;
            float v = 0.f;
            if (yy >= 0 && yy < H_ && xx >= 0 && xx < W_)
                v = xb[(size_t)(ci0 + s) * HW_ + yy * W_ + xx];
            xs[s][row][col] = v;
        }
        __syncthreads();
#pragma unroll
        for (int s = 0; s < 4; ++s) {
            float xv[9];
#pragma unroll
            for (int dy = 0; dy < 3; ++dy)
#pragma unroll
                for (int dx = 0; dx < 3; ++dx)
                    xv[dy * 3 + dx] = xs[s][ty + dy][tx + dx];
            const float* wp = w1 + ((size_t)oc0 * C_ + (ci0 + s)) * 9;
#pragma unroll
            for (int o = 0; o < 32; ++o) {
                const float* w = wp + (size_t)o * C_ * 9;  // uniform -> s_load
                acc[o] += w[0] * xv[0] + w[1] * xv[1] + w[2] * xv[2]
                        + w[3] * xv[3] + w[4] * xv[4] + w[5] * xv[5]
                        + w[6] * xv[6] + w[7] * xv[7] + w[8] * xv[8];
            }
        }
    }
#pragma unroll
    for (int o = 0; o < 32; ++o) {
        float r = fmaxf(acc[o] + b1[oc0 + o], 0.f);
#pragma unroll
        for (int k = 0; k < K; ++k)
            lacc[k] += w2[(size_t)k * C_ + oc0 + o] * r;
    }
#pragma unroll
    for (int k = 0; k < K; ++k)
        part[((size_t)(ch * B_ + b) * K + k) * HW_ + gy * W_ + gx] = lacc[k];
}

// Sum the 8 chunk-partials into the final logits (d_out region).
__global__ __launch_bounds__(256)
void head_reduce_kernel(const float* __restrict__ part, float* __restrict__ logits,
                        int K, int NCH)
{
    int i = blockIdx.x * 256 + threadIdx.x;
    int n = B_ * K * HW_;
    if (i >= n) return;
    int b = i / (K * HW_);
    int rem = i - b * K * HW_;
    float s = 0.f;
    for (int ch = 0; ch < NCH; ++ch)
        s += part[(size_t)(ch * B_ + b) * K * HW_ + rem];
    logits[i] = s;
}

// ---------------------------------------------------------------------------
// Generic conv3x3 + bias + relu (contact branch). grid (12,12, B*nsplit).
// ---------------------------------------------------------------------------
template<int OCCH>
__global__ __launch_bounds__(64)
void conv3_relu_kernel(const float* __restrict__ in,
                       const float* __restrict__ w, const float* __restrict__ bias,
                       float* __restrict__ out, int Cin, int Cout, int nsplit)
{
    const int tid = threadIdx.x;
    const int tx = tid & 7, ty = tid >> 3;
    const int x0 = blockIdx.x * 8, y0 = blockIdx.y * 8;
    const int b  = blockIdx.z / nsplit;
    const int sp = blockIdx.z % nsplit;
    const int oc0 = sp * OCCH;
    const int gx = x0 + tx, gy = y0 + ty;

    __shared__ float xs[4][10][12];

    float acc[OCCH];
#pragma unroll
    for (int o = 0; o < OCCH; ++o) acc[o] = 0.f;

    const float* xb = in + (size_t)b * Cin * HW_;

#pragma unroll 1
    for (int ci0 = 0; ci0 < Cin; ci0 += 4) {
        __syncthreads();
        for (int t = tid; t < 400; t += 64) {
            int s = t / 100, r = t % 100;
            int row = r / 10, col = r % 10;
            int yy = y0 - 1 + row, xx = x0 - 1 + col;
            float v = 0.f;
            if (yy >= 0 && yy < H_ && xx >= 0 && xx < W_)
                v = xb[(size_t)(ci0 + s) * HW_ + yy * W_ + xx];
            xs[s][row][col] = v;
        }
        __syncthreads();
#pragma unroll
        for (int s = 0; s < 4; ++s) {
            float xv[9];
#pragma unroll
            for (int dy = 0; dy < 3; ++dy)
#pragma unroll
                for (int dx = 0; dx < 3; ++dx)
                    xv[dy * 3 + dx] = xs[s][ty + dy][tx + dx];
            const float* wp = w + ((size_t)oc0 * Cin + (ci0 + s)) * 9;
#pragma unroll
            for (int o = 0; o < OCCH; ++o) {
                const float* wr = wp + (size_t)o * Cin * 9;
                acc[o] += wr[0] * xv[0] + wr[1] * xv[1] + wr[2] * xv[2]
                        + wr[3] * xv[3] + wr[4] * xv[4] + wr[5] * xv[5]
                        + wr[6] * xv[6] + wr[7] * xv[7] + wr[8] * xv[8];
            }
        }
    }
#pragma unroll
    for (int o = 0; o < OCCH; ++o)
        out[(size_t)(b * Cout + oc0 + o) * HW_ + gy * W_ + gx] =
            fmaxf(acc[o] + bias[oc0 + o], 0.f);
}

// ---------------------------------------------------------------------------
// Softmax / mask / NMS-score kernels
// ---------------------------------------------------------------------------
// 2-class heads: mask is identity on channel 0 (argmax over a single channel).
__global__ __launch_bounds__(256)
void prob2_kernel(const float* __restrict__ logits, float* __restrict__ p0)
{
    int i = blockIdx.x * 256 + threadIdx.x;
    if (i >= B_ * HW_) return;
    int b = i / HW_, pix = i - b * HW_;
    float l0 = logits[(size_t)b * 2 * HW_ + pix];
    float l1 = logits[(size_t)b * 2 * HW_ + HW_ + pix];
    float m = fmaxf(l0, l1);
    float e0 = expf(l0 - m), e1 = expf(l1 - m);
    p0[i] = e0 / (e0 + e1);
}

__global__ __launch_bounds__(256)
void score2_kernel(const float* __restrict__ p, float* __restrict__ sc)
{
    int i = blockIdx.x * 256 + threadIdx.x;
    if (i >= B_ * HW_) return;
    int pix = i % HW_;
    int yy = pix / W_, xx = pix - (pix / W_) * W_;
    float c = p[i];
    bool ok = (c >= EPS_);
    const float* pb = p + (i - pix);
#pragma unroll
    for (int dy = -1; dy <= 1; ++dy)
#pragma unroll
        for (int dx = -1; dx <= 1; ++dx) {
            if (dy == 0 && dx == 0) continue;
            int ny = yy + dy, nx = xx + dx;
            float v = 0.f;
            if (ny >= 0 && ny < H_ && nx >= 0 && nx < W_) v = pb[ny * W_ + nx];
            ok = ok && (c >= v);
        }
    sc[i] = c + (ok ? 1.f : 0.f);
}

// obj head: per pixel, masked map keeps only the argmax(first 10) channel.
__global__ __launch_bounds__(256)
void probobj_kernel(const float* __restrict__ logits, float* __restrict__ pval,
                    int* __restrict__ cstar)
{
    int i = blockIdx.x * 256 + threadIdx.x;
    if (i >= B_ * HW_) return;
    int b = i / HW_, pix = i - b * HW_;
    const float* lb = logits + (size_t)b * 11 * HW_ + pix;
    float l[11];
#pragma unroll
    for (int c2 = 0; c2 < 11; ++c2) l[c2] = lb[(size_t)c2 * HW_];
    float m = l[0];
#pragma unroll
    for (int c2 = 1; c2 < 11; ++c2) m = fmaxf(m, l[c2]);
    float sum = 0.f;
#pragma unroll
    for (int c2 = 0; c2 < 11; ++c2) sum += expf(l[c2] - m);
    int a = 0; float bestl = l[0];
#pragma unroll
    for (int c2 = 1; c2 < 10; ++c2)
        if (l[c2] > bestl) { bestl = l[c2]; a = c2; }   // first-max tie break
    pval[i] = expf(bestl - m) / sum;
    cstar[i] = a;
}

__global__ __launch_bounds__(256)
void score11_kernel(const float* __restrict__ p, const int* __restrict__ cs,
                    float* __restrict__ sc)
{
    int i = blockIdx.x * 256 + threadIdx.x;
    if (i >= B_ * HW_) return;
    int pix = i % HW_;
    int yy = pix / W_, xx = pix - (pix / W_) * W_;
    float c = p[i];
    int cc = cs[i];
    bool ok = (c >= EPS_);
    int base = i - pix;
#pragma unroll
    for (int dy = -1; dy <= 1; ++dy)
#pragma unroll
        for (int dx = -1; dx <= 1; ++dx) {
            if (dy == 0 && dx == 0) continue;
            int ny = yy + dy, nx = xx + dx;
            float v = 0.f;
            if (ny >= 0 && ny < H_ && nx >= 0 && nx < W_) {
                int n = base + ny * W_ + nx;
                v = (cs[n] == cc) ? p[n] : 0.f;   // neighbor in the same masked channel
            }
            ok = ok && (c >= v);
        }
    sc[i] = c + (ok ? 1.f : 0.f);
}

// ---------------------------------------------------------------------------
// top-k by iterative argmax (matches jax.lax.top_k: desc value, lower idx first)
// grid (3 heads, B). k = 40/40/20.
// ---------------------------------------------------------------------------
__global__ __launch_bounds__(256)
void topk_kernel(const float* __restrict__ scL, const float* __restrict__ scR,
                 const float* __restrict__ scO, int* __restrict__ idx)
{
    __shared__ float sv[HW_];
    __shared__ float rv[256];
    __shared__ int   ri[256];
    const int h = blockIdx.x, b = blockIdx.y;
    const float* src = (h == 0) ? scL : (h == 1) ? scR : scO;
    const int k = (h == 2) ? 20 : 40;
    const int off = b * NQ_ + ((h == 0) ? 0 : (h == 1) ? 40 : 80);

    for (int t = threadIdx.x; t < HW_; t += 256) sv[t] = src[(size_t)b * HW_ + t];
    __syncthreads();

    for (int kk = 0; kk < k; ++kk) {
        float bestv = -FLT_MAX; int besti = HW_;
        for (int t = threadIdx.x; t < HW_; t += 256) {
            float v = sv[t];
            if (v > bestv) { bestv = v; besti = t; }   // strided scan: first hit = lowest idx
        }
        rv[threadIdx.x] = bestv; ri[threadIdx.x] = besti;
        __syncthreads();
        for (int s = 128; s > 0; s >>= 1) {
            if (threadIdx.x < s) {
                float v2 = rv[threadIdx.x + s]; int i2 = ri[threadIdx.x + s];
                if (v2 > rv[threadIdx.x] ||
                    (v2 == rv[threadIdx.x] && i2 < ri[threadIdx.x])) {
                    rv[threadIdx.x] = v2; ri[threadIdx.x] = i2;
                }
            }
            __syncthreads();
        }
        if (threadIdx.x == 0) { idx[off + kk] = ri[0]; sv[ri[0]] = -FLT_MAX; }
        __syncthreads();
    }
}

// ---------------------------------------------------------------------------
// Contact branch tail
// ---------------------------------------------------------------------------
// mean over W then adaptive_avg_pool_1d(96 -> 778). block = one (b,c).
__global__ __launch_bounds__(128)
void pool_kernel(const float* __restrict__ h2, float* __restrict__ pooled)
{
    int bc = blockIdx.x;            // b*32 + c
    __shared__ float row[96];
    for (int hh = threadIdx.x; hh < 96; hh += 128) {
        const float* p = h2 + (size_t)bc * HW_ + hh * W_;
        float s = 0.f;
        for (int ww = 0; ww < 96; ++ww) s += p[ww];
        row[hh] = s * (1.f / 96.f);
    }
    __syncthreads();
    for (int i = threadIdx.x; i < 778; i += 128) {
        int s0 = (i * 96) / 778;
        int e0 = ((i + 1) * 96 + 777) / 778;   // ceil
        float s = 0.f;
        for (int t = s0; t < e0; ++t) s += row[t];
        pooled[(size_t)bc * 778 + i] = s / (float)(e0 - s0);
    }
}

// cm[b,j] = sum_k pooled[b,k] * cm_lw[j,k] + cm_lb[j]; one block per j.
__global__ __launch_bounds__(256)
void cm_kernel(const float* __restrict__ pooled, const float* __restrict__ cm_lw,
               const float* __restrict__ cm_lb, float* __restrict__ out5)
{
    const int j = blockIdx.x;
    const float* wr = cm_lw + (size_t)j * 24896;
    float acc[8];
#pragma unroll
    for (int b = 0; b < 8; ++b) acc[b] = 0.f;
    for (int t = threadIdx.x; t < 24896; t += 256) {
        float w = wr[t];
#pragma unroll
        for (int b = 0; b < 8; ++b) acc[b] += w * pooled[(size_t)b * 24896 + t];
    }
    __shared__ float red[8][256];
#pragma unroll
    for (int b = 0; b < 8; ++b) red[b][threadIdx.x] = acc[b];
    __syncthreads();
    for (int s = 128; s > 0; s >>= 1) {
        if (threadIdx.x < s) {
#pragma unroll
            for (int b = 0; b < 8; ++b) red[b][threadIdx.x] += red[b][threadIdx.x + s];
        }
        __syncthreads();
    }
    if (threadIdx.x < 8)
        out5[(size_t)threadIdx.x * 1556 + j] = red[threadIdx.x][0] + cm_lb[j];
}

// conv1d (VALID) + mean over t, via window sums. block = one batch, thread = oc.
__global__ __launch_bounds__(256)
void c1d_kernel(const float* __restrict__ cmap, const float* __restrict__ w,
                const float* __restrict__ bias, float* __restrict__ ccmean)
{
    int b = blockIdx.x;
    __shared__ float r[2][778];
    __shared__ float T[2][3];
    for (int t = threadIdx.x; t < 1556; t += 256)
        r[t / 778][t % 778] = cmap[(size_t)b * 1556 + t];
    __syncthreads();
    if (threadIdx.x < 2) {
        int ic = threadIdx.x;
        float s = 0.f;
        for (int i2 = 0; i2 < 778; ++i2) s += r[ic][i2];
        T[ic][0] = s - r[ic][776] - r[ic][777];
        T[ic][1] = s - r[ic][0]   - r[ic][777];
        T[ic][2] = s - r[ic][0]   - r[ic][1];
    }
    __syncthreads();
    int oc = threadIdx.x;
    float a = 0.f;
#pragma unroll
    for (int ic = 0; ic < 2; ++ic)
#pragma unroll
        for (int k = 0; k < 3; ++k)
            a += w[oc * 6 + ic * 3 + k] * T[ic][k];
    ccmean[b * 256 + oc] = a / 776.f + bias[oc];
}

// feat[b, j] = ccmean[b,:] . q_lw[j,:] + q_lb[j]
__global__ __launch_bounds__(256)
void feat_kernel(const float* __restrict__ ccmean, const float* __restrict__ q_lw,
                 const float* __restrict__ q_lb, float* __restrict__ feat)
{
    __shared__ float cc[8][256];
    for (int t = threadIdx.x; t < 2048; t += 256) cc[t >> 8][t & 255] = ccmean[t];
    __syncthreads();
    int j = blockIdx.x * 256 + threadIdx.x;
    const float* wr = q_lw + (size_t)j * 256;
    float acc[8];
#pragma unroll
    for (int b = 0; b < 8; ++b) acc[b] = 0.f;
    for (int c = 0; c < 256; ++c) {
        float wv = wr[c];
#pragma unroll
        for (int b = 0; b < 8; ++b) acc[b] += wv * cc[b][c];
    }
    float qb = q_lb[j];
#pragma unroll
    for (int b = 0; b < 8; ++b) feat[(size_t)b * 25600 + j] = acc[b] + qb;
}

// final gathers: out0 = x[...,idx] + feat, out1 = pos[...,idx]
__global__ __launch_bounds__(256)
void gather_kernel(const float* __restrict__ x, const float* __restrict__ pos,
                   const float* __restrict__ feat, const int* __restrict__ idx,
                   float* __restrict__ out0, float* __restrict__ out1)
{
    int t = blockIdx.x * 256 + threadIdx.x;
    if (t >= B_ * C_ * NQ_) return;
    int q = t % NQ_;
    int c2 = (t / NQ_) % C_;
    int b = t / (C_ * NQ_);
    int p = idx[b * NQ_ + q];
    out0[t] = x[((size_t)b * C_ + c2) * HW_ + p] + feat[(size_t)b * 25600 + c2 * NQ_ + q];
    out1[t] = pos[(size_t)c2 * HW_ + p];
}

// ---------------------------------------------------------------------------
extern "C" void kernel_launch(void* const* d_in, const int* in_sizes, int n_in,
                              void* d_out, int out_size, void* d_ws, size_t ws_size,
                              hipStream_t stream) {
    const float* x    = (const float*)d_in[0];
    const float* y    = (const float*)d_in[1];
    const float* pos  = (const float*)d_in[2];
    const float* lw1  = (const float*)d_in[3];  const float* lb1 = (const float*)d_in[4];
    const float* lw2  = (const float*)d_in[5];  const float* lb2 = (const float*)d_in[6];
    const float* rw1  = (const float*)d_in[7];  const float* rb1 = (const float*)d_in[8];
    const float* rw2  = (const float*)d_in[9];  const float* rb2 = (const float*)d_in[10];
    const float* ow1  = (const float*)d_in[11]; const float* ob1 = (const float*)d_in[12];
    const float* ow2  = (const float*)d_in[13]; const float* ob2 = (const float*)d_in[14];
    const float* cw1  = (const float*)d_in[15]; const float* cb1 = (const float*)d_in[16];
    const float* cw2  = (const float*)d_in[17]; const float* cb2 = (const float*)d_in[18];
    const float* cmlw = (const float*)d_in[19]; const float* cmlb = (const float*)d_in[20];
    const float* c1dw = (const float*)d_in[21]; const float* c1db = (const float*)d_in[22];
    const float* qlw  = (const float*)d_in[23]; const float* qlb  = (const float*)d_in[24];

    float* out  = (float*)d_out;
    float* out0 = out;                 // topk_proposals [8,256,100]
    float* out1 = out + 204800;        // topk_pos       [8,256,100]
    float* out2 = out + 409600;        // left_logits    [8,2,96,96]
    float* out3 = out + 557056;        // right_logits   [8,2,96,96]
    float* out4 = out + 704512;        // obj_logits     [8,11,96,96]
    float* out5 = out + 1515520;       // contact_map    [8,2,778,1]

    float* ws = (float*)d_ws;
    // region [0, 7,077,888): h1 (4.72M) + h2 (2.36M); later reused for head
    // partials (max 6.49M) and then prob/score maps (0.44M) -- all sequential.
    float* h1     = ws;
    float* h2     = ws + 4718592;
    float* part   = ws;                       // up to 8*8*11*9216 = 6,488,064
    float* pmap   = ws;                       // 73728
    int*   csmap  = (int*)(ws + 73728);       // 73728
    float* scL    = ws + 147456;              // 73728
    float* scR    = ws + 221184;              // 73728
    float* scO    = ws + 294912;              // 73728
    float* pooled = ws + 7077888;             // 199168
    float* ccmean = ws + 7277056;             // 2048
    float* feat   = ws + 7279104;             // 204800
    int*   idxb   = (int*)(ws + 7483904);     // 800
    (void)in_sizes; (void)n_in; (void)out_size; (void)ws_size;

    dim3 cgrid(12, 12, 8);

    // ---- contact branch (uses h1/h2 first, freed before heads) ----
    conv3_relu_kernel<32><<<dim3(12, 12, 16), 64, 0, stream>>>(y,  cw1, cb1, h1, 256, 64, 2);
    conv3_relu_kernel<32><<<cgrid,            64, 0, stream>>>(h1, cw2, cb2, h2, 64, 32, 1);
    pool_kernel<<<256, 128, 0, stream>>>(h2, pooled);
    cm_kernel<<<1556, 256, 0, stream>>>(pooled, cmlw, cmlb, out5);
    c1d_kernel<<<8, 256, 0, stream>>>(out5, c1dw, c1db, ccmean);
    feat_kernel<<<100, 256, 0, stream>>>(ccmean, qlw, qlb, feat);

    // ---- three heads (sequential reuse of `part`) ----
    dim3 hgrid(12, 12, 64);
    head_part_kernel<2><<<hgrid, 64, 0, stream>>>(x, lw1, lb1, lw2, lb2, part);
    head_reduce_kernel<<<576, 256, 0, stream>>>(part, out2, 2, 8);
    head_part_kernel<2><<<hgrid, 64, 0, stream>>>(x, rw1, rb1, rw2, rb2, part);
    head_reduce_kernel<<<576, 256, 0, stream>>>(part, out3, 2, 8);
    head_part_kernel<11><<<hgrid, 64, 0, stream>>>(x, ow1, ob1, ow2, ob2, part);
    head_reduce_kernel<<<3168, 256, 0, stream>>>(part, out4, 11, 8);

    // ---- probs / NMS scores (reuse region, heads complete) ----
    prob2_kernel<<<288, 256, 0, stream>>>(out2, pmap);
    score2_kernel<<<288, 256, 0, stream>>>(pmap, scL);
    prob2_kernel<<<288, 256, 0, stream>>>(out3, pmap);
    score2_kernel<<<288, 256, 0, stream>>>(pmap, scR);
    probobj_kernel<<<288, 256, 0, stream>>>(out4, pmap, csmap);
    score11_kernel<<<288, 256, 0, stream>>>(pmap, csmap, scO);

    // ---- topk + gathers ----
    topk_kernel<<<dim3(3, 8), 256, 0, stream>>>(scL, scR, scO, idxb);
    gather_kernel<<<800, 256, 0, stream>>>(x, pos, feat, idxb, out0, out1);
}

// Round 2
// 1405.896 us; speedup vs baseline: 14.5462x; 14.5462x over previous
//
#include <hip/hip_runtime.h>
#include <float.h>
#include <math.h>

#define B_ 8
#define C_ 256
#define H_ 96
#define W_ 96
#define HW_ 9216
#define TOTPIX_ 73728
#define NQ_ 100
#define EPS_ 1e-6f

typedef unsigned short ushort_t;
typedef __attribute__((ext_vector_type(8))) short bf16x8;
typedef __attribute__((ext_vector_type(4))) float f32x4;

typedef __attribute__((address_space(3))) unsigned int as3_u32;
typedef __attribute__((address_space(1))) unsigned int as1_u32;

// global -> LDS async 16B copy. LDS dest = wave-uniform base + lane*16.
__device__ __forceinline__ void gl16(const void* g, void* l) {
    __builtin_amdgcn_global_load_lds(
        (const as1_u32*)(unsigned long long)g,
        (as3_u32*)(unsigned int)(unsigned long long)l, 16, 0, 0);
}

__device__ __forceinline__ ushort_t bf16_of(float v) {
    unsigned u = __float_as_uint(v);
    u += 0x7fffu + ((u >> 16) & 1u);
    return (ushort_t)(u >> 16);
}
__device__ __forceinline__ float f_of_bf16(ushort_t h) {
    return __uint_as_float((unsigned)h << 16);
}

// ---------------------------------------------------------------------------
// Transpose+split: in [b][C][HW] fp32 -> oh/ol [b*HW][C] bf16 hi/lo
// ---------------------------------------------------------------------------
__global__ __launch_bounds__(256)
void tsplit_kernel(const float* __restrict__ in, ushort_t* __restrict__ oh,
                   ushort_t* __restrict__ ol)
{
    __shared__ float T[32][33];
    const int tx = threadIdx.x & 31, ty = threadIdx.x >> 5;
    const int p0 = blockIdx.x * 32, ci0 = blockIdx.y * 32, b = blockIdx.z;
#pragma unroll
    for (int i = 0; i < 4; ++i)
        T[ty + 8*i][tx] = in[((size_t)b*C_ + ci0 + ty + 8*i)*HW_ + p0 + tx];
    __syncthreads();
#pragma unroll
    for (int i = 0; i < 4; ++i) {
        float v = T[tx][ty + 8*i];
        ushort_t hi = bf16_of(v);
        float lo = v - f_of_bf16(hi);
        size_t o = ((size_t)b*HW_ + p0 + ty + 8*i)*C_ + ci0 + tx;
        oh[o] = hi;
        ol[o] = bf16_of(lo);
    }
}

// ---------------------------------------------------------------------------
// Weight repack: w [oc][ci][3][3] fp32 -> wh/wl [tap][oc][ci] bf16 hi/lo
// ---------------------------------------------------------------------------
__global__ __launch_bounds__(256)
void repack_kernel(const float* __restrict__ w, ushort_t* __restrict__ wh,
                   ushort_t* __restrict__ wl, int Cout, int Cin)
{
    int id = blockIdx.x*256 + threadIdx.x;
    int tot = 9*Cout*Cin;
    if (id >= tot) return;
    int tap = id / (Cout*Cin);
    int r = id - tap*(Cout*Cin);
    int oc = r / Cin, ci = r - oc*Cin;
    float v = w[((size_t)oc*Cin + ci)*9 + tap];
    ushort_t hi = bf16_of(v);
    wh[id] = hi;
    wl[id] = bf16_of(v - f_of_bf16(hi));
}

// ---------------------------------------------------------------------------
// Implicit-GEMM conv3x3 (pad=1) via MFMA, split-bf16 3-term accumulation.
//   A (global): Agh/Agl [73728 pix][CIN] bf16 hi/lo (transposed input)
//   W (global): Wgh/Wgl [9 taps][COUT][CIN] bf16 hi/lo
//   MODE 0: fused bias+relu+1x1(KK ch) -> out_logits [b][KK][HW] fp32
//   MODE 1: bias+relu -> Oth/Otl [pix][COUT] bf16 hi/lo (transposed, for next conv)
//   MODE 2: bias+relu -> outf [b][COUT][HW] fp32
// ---------------------------------------------------------------------------
template<int WM, int WN, int MF, int NF, int CIN, int MODE, int KK>
__global__ __launch_bounds__(WM*WN*64, 4)
void conv_gemm_kernel(const ushort_t* __restrict__ Agh, const ushort_t* __restrict__ Agl,
                      const ushort_t* __restrict__ Wgh, const ushort_t* __restrict__ Wgl,
                      const float* __restrict__ bias1,
                      const float* __restrict__ w2, const float* __restrict__ b2,
                      float* __restrict__ out_logits,
                      ushort_t* __restrict__ Oth, ushort_t* __restrict__ Otl,
                      float* __restrict__ outf)
{
    constexpr int NW   = WM*WN;
    constexpr int NT   = NW*64;
    constexpr int BM   = WM*MF*16;
    constexpr int COUT = WN*NF*16;
    constexpr int APAD = ((BM + 194 + 7) / 8) * 8;   // halo rows, %8
    constexpr int NCALL_A = (2*APAD*4)/64;           // 16B chunks / 64 lanes
    constexpr int NCALL_B = (2*COUT*4)/64;

    __shared__ __align__(16) ushort_t ALds[2*APAD*32];
    __shared__ __align__(16) ushort_t BLds[2*COUT*32];

    const int tid  = threadIdx.x;
    const int lane = tid & 63;
    const int wid  = __builtin_amdgcn_readfirstlane(tid >> 6);
    const int wm   = wid / WN, wn = wid % WN;
    const int l15  = lane & 15, l4 = lane >> 4;
    const int wmb  = wm * MF * 16;
    const int wnb  = wn * NF * 16;

    const int p0    = blockIdx.x * BM;
    const int bidx  = p0 / HW_;
    const int pimg0 = p0 - bidx * HW_;

    // per-(mf) 9-bit tap validity mask for this lane's A rows (row = l15)
    int vmask[MF];
#pragma unroll
    for (int mf = 0; mf < MF; ++mf) {
        int q  = pimg0 + wmb + mf*16 + l15;
        int yy = q / 96, xx = q - yy*96;
        int m = 0;
#pragma unroll
        for (int t = 0; t < 9; ++t) {
            int dy = t/3, dx = t - dy*3;
            if ((unsigned)(yy+dy-1) < 96u && (unsigned)(xx+dx-1) < 96u) m |= 1<<t;
        }
        vmask[mf] = m;
    }

    f32x4 acc[MF][NF];
#pragma unroll
    for (int i = 0; i < MF; ++i)
#pragma unroll
        for (int j = 0; j < NF; ++j) acc[i][j] = (f32x4){0.f,0.f,0.f,0.f};

#pragma unroll 1
    for (int ci0 = 0; ci0 < CIN; ci0 += 32) {
        // ---- stage A tile (halo rows, both splits), swizzled source ----
#pragma unroll 1
        for (int c = wid; c < NCALL_A; c += NW) {
            int id    = c*64 + lane;
            int split = id / (APAD*4);
            int r     = id - split*(APAD*4);
            int pix   = r >> 2, kg = r & 3;
            long P = (long)p0 - 97 + pix;
            P = P < 0 ? 0 : (P > (TOTPIX_-1) ? (TOTPIX_-1) : P);
            const ushort_t* src = (split ? Agl : Agh)
                + (size_t)P*CIN + ci0 + ((kg ^ (pix & 3)) << 3);
            gl16(src, ALds + (size_t)c*512);
        }
#pragma unroll 1
        for (int tap = 0; tap < 9; ++tap) {
            // ---- stage B tile for this tap (both splits), linear ----
#pragma unroll 1
            for (int c = wid; c < NCALL_B; c += NW) {
                int id    = c*64 + lane;
                int split = id / (COUT*4);
                int r     = id - split*(COUT*4);
                int n     = r >> 2, kg = r & 3;
                const ushort_t* src = (split ? Wgl : Wgh)
                    + ((size_t)tap*COUT + n)*CIN + ci0 + kg*8;
                gl16(src, BLds + (size_t)c*512);
            }
            __syncthreads();   // drains vmcnt -> staged data visible

            const int dy = tap/3, dx = tap - dy*3;
            const int offt = (dy-1)*96 + (dx-1);

            bf16x8 bh[NF], bl[NF];
#pragma unroll
            for (int nf = 0; nf < NF; ++nf) {
                int bi = (wnb + nf*16 + l15)*32 + l4*8;
                bh[nf] = *(const bf16x8*)&BLds[bi];
                bl[nf] = *(const bf16x8*)&BLds[bi + COUT*32];
            }
#pragma unroll
            for (int mf = 0; mf < MF; ++mf) {
                int row = wmb + mf*16 + l15 + 97 + offt;
                int ai  = row*32 + ((l4 ^ (row & 3)) << 3);
                bf16x8 ah = *(const bf16x8*)&ALds[ai];
                bf16x8 al = *(const bf16x8*)&ALds[ai + APAD*32];
                bool ok = (vmask[mf] >> tap) & 1;
                bf16x8 z = (bf16x8)(short)0;
                ah = ok ? ah : z;
                al = ok ? al : z;
#pragma unroll
                for (int nf = 0; nf < NF; ++nf) {
                    acc[mf][nf] = __builtin_amdgcn_mfma_f32_16x16x32_bf16(
                        ah, bh[nf], acc[mf][nf], 0, 0, 0);
                    acc[mf][nf] = __builtin_amdgcn_mfma_f32_16x16x32_bf16(
                        al, bh[nf], acc[mf][nf], 0, 0, 0);
                    acc[mf][nf] = __builtin_amdgcn_mfma_f32_16x16x32_bf16(
                        ah, bl[nf], acc[mf][nf], 0, 0, 0);
                }
            }
            __syncthreads();   // protect LDS before next stage overwrites
        }
    }

    // ---------------- epilogue ----------------
    float biasv[NF];
#pragma unroll
    for (int nf = 0; nf < NF; ++nf) biasv[nf] = bias1[wnb + nf*16 + l15];

    if constexpr (MODE == 0) {
        // fused 1x1: logits[k][m] = sum_n w2[k][n]*relu(acc+bias) + b2[k]
        float* Lacc = (float*)BLds;   // [WN][BM][KK], each slot written once
        float w2v[NF][KK];
#pragma unroll
        for (int nf = 0; nf < NF; ++nf)
#pragma unroll
            for (int k = 0; k < KK; ++k)
                w2v[nf][k] = w2[(size_t)k*COUT + wnb + nf*16 + l15];

#pragma unroll
        for (int mf = 0; mf < MF; ++mf) {
#pragma unroll
            for (int reg = 0; reg < 4; ++reg) {
                float v[KK];
#pragma unroll
                for (int k = 0; k < KK; ++k) v[k] = 0.f;
#pragma unroll
                for (int nf = 0; nf < NF; ++nf) {
                    float r = fmaxf(acc[mf][nf][reg] + biasv[nf], 0.f);
#pragma unroll
                    for (int k = 0; k < KK; ++k) v[k] += r * w2v[nf][k];
                }
#pragma unroll
                for (int k = 0; k < KK; ++k) {
                    v[k] += __shfl_xor(v[k], 1);
                    v[k] += __shfl_xor(v[k], 2);
                    v[k] += __shfl_xor(v[k], 4);
                    v[k] += __shfl_xor(v[k], 8);
                }
                if (l15 == 0) {
                    int mrow = wmb + mf*16 + l4*4 + reg;
#pragma unroll
                    for (int k = 0; k < KK; ++k)
                        Lacc[((size_t)wn*BM + mrow)*KK + k] = v[k];
                }
            }
        }
        __syncthreads();
        for (int i = tid; i < BM*KK; i += NT) {
            int mrow = i / KK, k = i - mrow*KK;
            float s = b2[k];
#pragma unroll
            for (int w = 0; w < WN; ++w) s += Lacc[((size_t)w*BM + mrow)*KK + k];
            out_logits[((size_t)bidx*KK + k)*HW_ + pimg0 + mrow] = s;
        }
    } else if constexpr (MODE == 1) {
        // bf16 hi/lo transposed output [pix][COUT]
#pragma unroll
        for (int mf = 0; mf < MF; ++mf)
#pragma unroll
            for (int nf = 0; nf < NF; ++nf)
#pragma unroll
                for (int reg = 0; reg < 4; ++reg) {
                    float r = fmaxf(acc[mf][nf][reg] + biasv[nf], 0.f);
                    ushort_t hi = bf16_of(r);
                    float lo = r - f_of_bf16(hi);
                    size_t P = (size_t)p0 + wmb + mf*16 + l4*4 + reg;
                    size_t o = P*COUT + wnb + nf*16 + l15;
                    Oth[o] = hi;
                    Otl[o] = bf16_of(lo);
                }
    } else {
        // fp32 NCHW output
#pragma unroll
        for (int mf = 0; mf < MF; ++mf)
#pragma unroll
            for (int nf = 0; nf < NF; ++nf)
#pragma unroll
                for (int reg = 0; reg < 4; ++reg) {
                    float r = fmaxf(acc[mf][nf][reg] + biasv[nf], 0.f);
                    int mrow = wmb + mf*16 + l4*4 + reg;
                    outf[((size_t)bidx*COUT + wnb + nf*16 + l15)*HW_ + pimg0 + mrow] = r;
                }
    }
}

// ---------------------------------------------------------------------------
// Softmax / mask / NMS-score kernels (unchanged from round 1 — verified)
// ---------------------------------------------------------------------------
__global__ __launch_bounds__(256)
void prob2_kernel(const float* __restrict__ logits, float* __restrict__ p0)
{
    int i = blockIdx.x * 256 + threadIdx.x;
    if (i >= B_ * HW_) return;
    int b = i / HW_, pix = i - b * HW_;
    float l0 = logits[(size_t)b * 2 * HW_ + pix];
    float l1 = logits[(size_t)b * 2 * HW_ + HW_ + pix];
    float m = fmaxf(l0, l1);
    float e0 = expf(l0 - m), e1 = expf(l1 - m);
    p0[i] = e0 / (e0 + e1);
}

__global__ __launch_bounds__(256)
void score2_kernel(const float* __restrict__ p, float* __restrict__ sc)
{
    int i = blockIdx.x * 256 + threadIdx.x;
    if (i >= B_ * HW_) return;
    int pix = i % HW_;
    int yy = pix / W_, xx = pix - (pix / W_) * W_;
    float c = p[i];
    bool ok = (c >= EPS_);
    const float* pb = p + (i - pix);
#pragma unroll
    for (int dy = -1; dy <= 1; ++dy)
#pragma unroll
        for (int dx = -1; dx <= 1; ++dx) {
            if (dy == 0 && dx == 0) continue;
            int ny = yy + dy, nx = xx + dx;
            float v = 0.f;
            if (ny >= 0 && ny < H_ && nx >= 0 && nx < W_) v = pb[ny * W_ + nx];
            ok = ok && (c >= v);
        }
    sc[i] = c + (ok ? 1.f : 0.f);
}

__global__ __launch_bounds__(256)
void probobj_kernel(const float* __restrict__ logits, float* __restrict__ pval,
                    int* __restrict__ cstar)
{
    int i = blockIdx.x * 256 + threadIdx.x;
    if (i >= B_ * HW_) return;
    int b = i / HW_, pix = i - b * HW_;
    const float* lb = logits + (size_t)b * 11 * HW_ + pix;
    float l[11];
#pragma unroll
    for (int c2 = 0; c2 < 11; ++c2) l[c2] = lb[(size_t)c2 * HW_];
    float m = l[0];
#pragma unroll
    for (int c2 = 1; c2 < 11; ++c2) m = fmaxf(m, l[c2]);
    float sum = 0.f;
#pragma unroll
    for (int c2 = 0; c2 < 11; ++c2) sum += expf(l[c2] - m);
    int a = 0; float bestl = l[0];
#pragma unroll
    for (int c2 = 1; c2 < 10; ++c2)
        if (l[c2] > bestl) { bestl = l[c2]; a = c2; }
    pval[i] = expf(bestl - m) / sum;
    cstar[i] = a;
}

__global__ __launch_bounds__(256)
void score11_kernel(const float* __restrict__ p, const int* __restrict__ cs,
                    float* __restrict__ sc)
{
    int i = blockIdx.x * 256 + threadIdx.x;
    if (i >= B_ * HW_) return;
    int pix = i % HW_;
    int yy = pix / W_, xx = pix - (pix / W_) * W_;
    float c = p[i];
    int cc = cs[i];
    bool ok = (c >= EPS_);
    int base = i - pix;
#pragma unroll
    for (int dy = -1; dy <= 1; ++dy)
#pragma unroll
        for (int dx = -1; dx <= 1; ++dx) {
            if (dy == 0 && dx == 0) continue;
            int ny = yy + dy, nx = xx + dx;
            float v = 0.f;
            if (ny >= 0 && ny < H_ && nx >= 0 && nx < W_) {
                int n = base + ny * W_ + nx;
                v = (cs[n] == cc) ? p[n] : 0.f;
            }
            ok = ok && (c >= v);
        }
    sc[i] = c + (ok ? 1.f : 0.f);
}

// ---------------------------------------------------------------------------
// top-k by iterative argmax (matches jax.lax.top_k ordering)
// ---------------------------------------------------------------------------
__global__ __launch_bounds__(256)
void topk_kernel(const float* __restrict__ scL, const float* __restrict__ scR,
                 const float* __restrict__ scO, int* __restrict__ idx)
{
    __shared__ float sv[HW_];
    __shared__ float rv[256];
    __shared__ int   ri[256];
    const int h = blockIdx.x, b = blockIdx.y;
    const float* src = (h == 0) ? scL : (h == 1) ? scR : scO;
    const int k = (h == 2) ? 20 : 40;
    const int off = b * NQ_ + ((h == 0) ? 0 : (h == 1) ? 40 : 80);

    for (int t = threadIdx.x; t < HW_; t += 256) sv[t] = src[(size_t)b * HW_ + t];
    __syncthreads();

    for (int kk = 0; kk < k; ++kk) {
        float bestv = -FLT_MAX; int besti = HW_;
        for (int t = threadIdx.x; t < HW_; t += 256) {
            float v = sv[t];
            if (v > bestv) { bestv = v; besti = t; }
        }
        rv[threadIdx.x] = bestv; ri[threadIdx.x] = besti;
        __syncthreads();
        for (int s = 128; s > 0; s >>= 1) {
            if (threadIdx.x < s) {
                float v2 = rv[threadIdx.x + s]; int i2 = ri[threadIdx.x + s];
                if (v2 > rv[threadIdx.x] ||
                    (v2 == rv[threadIdx.x] && i2 < ri[threadIdx.x])) {
                    rv[threadIdx.x] = v2; ri[threadIdx.x] = i2;
                }
            }
            __syncthreads();
        }
        if (threadIdx.x == 0) { idx[off + kk] = ri[0]; sv[ri[0]] = -FLT_MAX; }
        __syncthreads();
    }
}

// ---------------------------------------------------------------------------
// Contact branch tail (unchanged)
// ---------------------------------------------------------------------------
__global__ __launch_bounds__(128)
void pool_kernel(const float* __restrict__ h2, float* __restrict__ pooled)
{
    int bc = blockIdx.x;
    __shared__ float row[96];
    for (int hh = threadIdx.x; hh < 96; hh += 128) {
        const float* p = h2 + (size_t)bc * HW_ + hh * W_;
        float s = 0.f;
        for (int ww = 0; ww < 96; ++ww) s += p[ww];
        row[hh] = s * (1.f / 96.f);
    }
    __syncthreads();
    for (int i = threadIdx.x; i < 778; i += 128) {
        int s0 = (i * 96) / 778;
        int e0 = ((i + 1) * 96 + 777) / 778;
        float s = 0.f;
        for (int t = s0; t < e0; ++t) s += row[t];
        pooled[(size_t)bc * 778 + i] = s / (float)(e0 - s0);
    }
}

__global__ __launch_bounds__(256)
void cm_kernel(const float* __restrict__ pooled, const float* __restrict__ cm_lw,
               const float* __restrict__ cm_lb, float* __restrict__ out5)
{
    const int j = blockIdx.x;
    const float* wr = cm_lw + (size_t)j * 24896;
    float acc[8];
#pragma unroll
    for (int b = 0; b < 8; ++b) acc[b] = 0.f;
    for (int t = threadIdx.x; t < 24896; t += 256) {
        float w = wr[t];
#pragma unroll
        for (int b = 0; b < 8; ++b) acc[b] += w * pooled[(size_t)b * 24896 + t];
    }
    __shared__ float red[8][256];
#pragma unroll
    for (int b = 0; b < 8; ++b) red[b][threadIdx.x] = acc[b];
    __syncthreads();
    for (int s = 128; s > 0; s >>= 1) {
        if (threadIdx.x < s) {
#pragma unroll
            for (int b = 0; b < 8; ++b) red[b][threadIdx.x] += red[b][threadIdx.x + s];
        }
        __syncthreads();
    }
    if (threadIdx.x < 8)
        out5[(size_t)threadIdx.x * 1556 + j] = red[threadIdx.x][0] + cm_lb[j];
}

__global__ __launch_bounds__(256)
void c1d_kernel(const float* __restrict__ cmap, const float* __restrict__ w,
                const float* __restrict__ bias, float* __restrict__ ccmean)
{
    int b = blockIdx.x;
    __shared__ float r[2][778];
    __shared__ float T[2][3];
    for (int t = threadIdx.x; t < 1556; t += 256)
        r[t / 778][t % 778] = cmap[(size_t)b * 1556 + t];
    __syncthreads();
    if (threadIdx.x < 2) {
        int ic = threadIdx.x;
        float s = 0.f;
        for (int i2 = 0; i2 < 778; ++i2) s += r[ic][i2];
        T[ic][0] = s - r[ic][776] - r[ic][777];
        T[ic][1] = s - r[ic][0]   - r[ic][777];
        T[ic][2] = s - r[ic][0]   - r[ic][1];
    }
    __syncthreads();
    int oc = threadIdx.x;
    float a = 0.f;
#pragma unroll
    for (int ic = 0; ic < 2; ++ic)
#pragma unroll
        for (int k = 0; k < 3; ++k)
            a += w[oc * 6 + ic * 3 + k] * T[ic][k];
    ccmean[b * 256 + oc] = a / 776.f + bias[oc];
}

__global__ __launch_bounds__(256)
void feat_kernel(const float* __restrict__ ccmean, const float* __restrict__ q_lw,
                 const float* __restrict__ q_lb, float* __restrict__ feat)
{
    __shared__ float cc[8][256];
    for (int t = threadIdx.x; t < 2048; t += 256) cc[t >> 8][t & 255] = ccmean[t];
    __syncthreads();
    int j = blockIdx.x * 256 + threadIdx.x;
    const float* wr = q_lw + (size_t)j * 256;
    float acc[8];
#pragma unroll
    for (int b = 0; b < 8; ++b) acc[b] = 0.f;
    for (int c = 0; c < 256; ++c) {
        float wv = wr[c];
#pragma unroll
        for (int b = 0; b < 8; ++b) acc[b] += wv * cc[b][c];
    }
    float qb = q_lb[j];
#pragma unroll
    for (int b = 0; b < 8; ++b) feat[(size_t)b * 25600 + j] = acc[b] + qb;
}

__global__ __launch_bounds__(256)
void gather_kernel(const float* __restrict__ x, const float* __restrict__ pos,
                   const float* __restrict__ feat, const int* __restrict__ idx,
                   float* __restrict__ out0, float* __restrict__ out1)
{
    int t = blockIdx.x * 256 + threadIdx.x;
    if (t >= B_ * C_ * NQ_) return;
    int q = t % NQ_;
    int c2 = (t / NQ_) % C_;
    int b = t / (C_ * NQ_);
    int p = idx[b * NQ_ + q];
    out0[t] = x[((size_t)b * C_ + c2) * HW_ + p] + feat[(size_t)b * 25600 + c2 * NQ_ + q];
    out1[t] = pos[(size_t)c2 * HW_ + p];
}

// ---------------------------------------------------------------------------
extern "C" void kernel_launch(void* const* d_in, const int* in_sizes, int n_in,
                              void* d_out, int out_size, void* d_ws, size_t ws_size,
                              hipStream_t stream) {
    const float* x    = (const float*)d_in[0];
    const float* y    = (const float*)d_in[1];
    const float* pos  = (const float*)d_in[2];
    const float* lw1  = (const float*)d_in[3];  const float* lb1 = (const float*)d_in[4];
    const float* lw2  = (const float*)d_in[5];  const float* lb2 = (const float*)d_in[6];
    const float* rw1  = (const float*)d_in[7];  const float* rb1 = (const float*)d_in[8];
    const float* rw2  = (const float*)d_in[9];  const float* rb2 = (const float*)d_in[10];
    const float* ow1  = (const float*)d_in[11]; const float* ob1 = (const float*)d_in[12];
    const float* ow2  = (const float*)d_in[13]; const float* ob2 = (const float*)d_in[14];
    const float* cw1  = (const float*)d_in[15]; const float* cb1 = (const float*)d_in[16];
    const float* cw2  = (const float*)d_in[17]; const float* cb2 = (const float*)d_in[18];
    const float* cmlw = (const float*)d_in[19]; const float* cmlb = (const float*)d_in[20];
    const float* c1dw = (const float*)d_in[21]; const float* c1db = (const float*)d_in[22];
    const float* qlw  = (const float*)d_in[23]; const float* qlb  = (const float*)d_in[24];

    float* out  = (float*)d_out;
    float* out0 = out;                 // topk_proposals [8,256,100]
    float* out1 = out + 204800;        // topk_pos       [8,256,100]
    float* out2 = out + 409600;        // left_logits    [8,2,96,96]
    float* out3 = out + 557056;        // right_logits   [8,2,96,96]
    float* out4 = out + 704512;        // obj_logits     [8,11,96,96]
    float* out5 = out + 1515520;       // contact_map    [8,2,778,1]

    float* ws = (float*)d_ws;
    // R region: transposed bf16 hi/lo input (yt for contact phase, then xt)
    ushort_t* Rh   = (ushort_t*)(ws);                  // 73728*256 bf16
    ushort_t* Rl   = (ushort_t*)(ws + 9437184);
    ushort_t* h1h  = (ushort_t*)(ws + 18874368);       // 73728*64 bf16
    ushort_t* h1l  = (ushort_t*)(ws + 21233664);
    float*    h2   = ws + 23592960;                    // 8*32*9216 fp32
    ushort_t* wLh  = (ushort_t*)(ws + 25952256);       // 9*256*256 bf16 each
    ushort_t* wLl  = (ushort_t*)(ws + 26247168);
    ushort_t* wRh  = (ushort_t*)(ws + 26542080);
    ushort_t* wRl  = (ushort_t*)(ws + 26836992);
    ushort_t* wOh  = (ushort_t*)(ws + 27131904);
    ushort_t* wOl  = (ushort_t*)(ws + 27426816);
    ushort_t* wc1h = (ushort_t*)(ws + 27721728);       // 9*64*256
    ushort_t* wc1l = (ushort_t*)(ws + 27795456);
    ushort_t* wc2h = (ushort_t*)(ws + 27869184);       // 9*32*64
    ushort_t* wc2l = (ushort_t*)(ws + 27878400);
    float* pooled  = ws + 27887616;                    // 8*32*778
    float* ccmean  = ws + 28086784;                    // 2048
    float* feat    = ws + 28088832;                    // 204800
    float* pmap    = ws + 28293632;                    // 73728
    int*   csmap   = (int*)(ws + 28367360);            // 73728
    float* scL     = ws + 28441088;
    float* scR     = ws + 28514816;
    float* scO     = ws + 28588544;
    int*   idxb    = (int*)(ws + 28662272);            // 800
    (void)in_sizes; (void)n_in; (void)out_size; (void)ws_size; (void)pos;

    // ---- weight repacks ----
    repack_kernel<<<(9*256*256+255)/256, 256, 0, stream>>>(lw1, wLh, wLl, 256, 256);
    repack_kernel<<<(9*256*256+255)/256, 256, 0, stream>>>(rw1, wRh, wRl, 256, 256);
    repack_kernel<<<(9*256*256+255)/256, 256, 0, stream>>>(ow1, wOh, wOl, 256, 256);
    repack_kernel<<<(9*64*256+255)/256,  256, 0, stream>>>(cw1, wc1h, wc1l, 64, 256);
    repack_kernel<<<(9*32*64+255)/256,   256, 0, stream>>>(cw2, wc2h, wc2l, 32, 64);

    // ---- contact branch (uses R for yt; R freed after conv1) ----
    tsplit_kernel<<<dim3(288, 8, 8), 256, 0, stream>>>(y, Rh, Rl);
    conv_gemm_kernel<4,2,2,2,256,1,1><<<576, 512, 0, stream>>>(
        Rh, Rl, wc1h, wc1l, cb1, nullptr, nullptr, nullptr, h1h, h1l, nullptr);
    conv_gemm_kernel<4,2,2,1,64,2,1><<<576, 512, 0, stream>>>(
        h1h, h1l, wc2h, wc2l, cb2, nullptr, nullptr, nullptr, nullptr, nullptr, h2);
    pool_kernel<<<256, 128, 0, stream>>>(h2, pooled);
    cm_kernel<<<1556, 256, 0, stream>>>(pooled, cmlw, cmlb, out5);
    c1d_kernel<<<8, 256, 0, stream>>>(out5, c1dw, c1db, ccmean);
    feat_kernel<<<100, 256, 0, stream>>>(ccmean, qlw, qlb, feat);

    // ---- heads (R now holds xt) ----
    tsplit_kernel<<<dim3(288, 8, 8), 256, 0, stream>>>(x, Rh, Rl);
    conv_gemm_kernel<2,4,4,4,256,0,2><<<576, 512, 0, stream>>>(
        Rh, Rl, wLh, wLl, lb1, lw2, lb2, out2, nullptr, nullptr, nullptr);
    conv_gemm_kernel<2,4,4,4,256,0,2><<<576, 512, 0, stream>>>(
        Rh, Rl, wRh, wRl, rb1, rw2, rb2, out3, nullptr, nullptr, nullptr);
    conv_gemm_kernel<2,4,4,4,256,0,11><<<576, 512, 0, stream>>>(
        Rh, Rl, wOh, wOl, ob1, ow2, ob2, out4, nullptr, nullptr, nullptr);

    // ---- probs / NMS scores ----
    prob2_kernel<<<288, 256, 0, stream>>>(out2, pmap);
    score2_kernel<<<288, 256, 0, stream>>>(pmap, scL);
    prob2_kernel<<<288, 256, 0, stream>>>(out3, pmap);
    score2_kernel<<<288, 256, 0, stream>>>(pmap, scR);
    probobj_kernel<<<288, 256, 0, stream>>>(out4, pmap, csmap);
    score11_kernel<<<288, 256, 0, stream>>>(pmap, csmap, scO);

    // ---- topk + gathers ----
    topk_kernel<<<dim3(3, 8), 256, 0, stream>>>(scL, scR, scO, idxb);
    gather_kernel<<<800, 256, 0, stream>>>(x, pos, feat, idxb, out0, out1);
}